// Round 4
// baseline (9938.939 us; speedup 1.0000x reference)
//
#include <hip/hip_runtime.h>
#include <math.h>

// ---------------------------------------------------------------------------
// Seq2seq (GRU enc + attn GRU dec, teacher forcing) -> mean NLL scalar.
//   K1a: enc_gi[512][3072] = enc_emb[input] @ enc_W_ih^T + b_ih      (GEMM)
//   K1b: attn_e[512][512]  = dec_emb[dec_in] @ attn_W[:, :H]^T + attn_b
//   K1c: comb_e[512][1024] = dec_emb[dec_in] @ comb_W[:, :H]^T + comb_b
//   K2 : persistent encoder recurrence (512 steps, 1 exchange/step)
//   K3 : M[1024][512] = comb_W[:, H:] @ enc_outs^T                   (GEMM)
//   K4 : persistent decoder recurrence (512 steps, 3 exchanges/step)
//   K5 : logits GEMM [512,32000] + fused per-row (max, sumexp) partials
//   K6 : combine partials -> lse -> mean NLL -> d_out[0]
//
// Cross-block exchange: NCCL-LL-style mailboxes. Each float is packed with a
// monotonically-increasing phase tag into ONE 8B word and stored with a
// relaxed agent-scope u64 atomic store (atomic unit -> no data/flag ordering
// hazard, no vmcnt drain, no separate arrive). Consumers poll the data
// itself; on tag match the payload is already in registers. One exchange ~
// one IC round trip. Recurrence blocks are 64 threads (1 wave): all phases
// run in program order, no multi-wave sync overhead; weights LDS-resident.
// ---------------------------------------------------------------------------

#define H 1024
#define T 512
#define V 32000

typedef unsigned long long u64;

// -------- LL mailbox primitives (relaxed agent scope, no cache maint) ------
__device__ __forceinline__ void ll_store(u64* seg, float v, unsigned tag) {
    u64 p = ((u64)tag << 32) | (u64)__float_as_uint(v);
    __hip_atomic_store(seg, p, __ATOMIC_RELAXED, __HIP_MEMORY_SCOPE_AGENT);
}
// poll 512-seg buffer: lane gets segs {lane+64j}, j<8
__device__ __forceinline__ void ll_poll8(const u64* buf, unsigned tag, int lane,
                                         float* out) {
    u64 v[8];
    for (;;) {
        #pragma unroll
        for (int j = 0; j < 8; ++j)
            v[j] = __hip_atomic_load(buf + lane + 64 * j, __ATOMIC_RELAXED,
                                     __HIP_MEMORY_SCOPE_AGENT);
        int ok = 1;
        #pragma unroll
        for (int j = 0; j < 8; ++j) ok &= ((unsigned)(v[j] >> 32) >= tag);
        if (__all(ok)) break;
    }
    #pragma unroll
    for (int j = 0; j < 8; ++j) out[j] = __uint_as_float((unsigned)v[j]);
}
// poll 1024-seg buffer: lane gets segs {lane+64j}, j<16
__device__ __forceinline__ void ll_poll16(const u64* buf, unsigned tag, int lane,
                                          float* out) {
    u64 v[16];
    for (;;) {
        #pragma unroll
        for (int j = 0; j < 16; ++j)
            v[j] = __hip_atomic_load(buf + lane + 64 * j, __ATOMIC_RELAXED,
                                     __HIP_MEMORY_SCOPE_AGENT);
        int ok = 1;
        #pragma unroll
        for (int j = 0; j < 16; ++j) ok &= ((unsigned)(v[j] >> 32) >= tag);
        if (__all(ok)) break;
    }
    #pragma unroll
    for (int j = 0; j < 16; ++j) out[j] = __uint_as_float((unsigned)v[j]);
}

__device__ __forceinline__ float sigmoidf_(float x) { return 1.f / (1.f + expf(-x)); }

// ------------------------- generic tiled GEMM ------------------------------
// C[t,n] = sum_k Xrow(t)[k] * Wrow(n)[k] (+ bias[n])
// Xrow(t): gmode 0 -> X + t*xs + xo ; 1 -> X + idx[t]*xs + xo ;
//          2 -> X + ((t==0)?0:idx[t-1])*xs + xo   (teacher-forced dec input)
__global__ __launch_bounds__(256) void gemm_tn(
    const float* __restrict__ X, int xs, int xo,
    const int* __restrict__ gidx, int gmode,
    const float* __restrict__ W, int wsd, int wo,
    const float* __restrict__ bias,
    float* __restrict__ C, int cs, int K)
{
    __shared__ float A_lds[32][64];
    __shared__ float B_lds[32][64];
    const int tid = threadIdx.x;
    const int tx = tid & 15, ty = tid >> 4;
    const int n0 = blockIdx.x * 64, t0 = blockIdx.y * 64;
    float acc[4][4] = {};

    for (int k0 = 0; k0 < K; k0 += 32) {
        #pragma unroll
        for (int q = 0; q < 2; ++q) {
            int f4 = tid + q * 256;          // 0..511
            int row = f4 >> 3, c4 = f4 & 7;
            int trow = t0 + row;
            const float* xr;
            if (gmode == 0)      xr = X + (size_t)trow * xs + xo;
            else if (gmode == 1) xr = X + (size_t)gidx[trow] * xs + xo;
            else { int tok = (trow == 0) ? 0 : gidx[trow - 1];
                   xr = X + (size_t)tok * xs + xo; }
            float4 a = *(const float4*)(xr + k0 + c4 * 4);
            A_lds[c4*4+0][row] = a.x; A_lds[c4*4+1][row] = a.y;
            A_lds[c4*4+2][row] = a.z; A_lds[c4*4+3][row] = a.w;
            const float* wr = W + (size_t)(n0 + row) * wsd + wo;
            float4 b = *(const float4*)(wr + k0 + c4 * 4);
            B_lds[c4*4+0][row] = b.x; B_lds[c4*4+1][row] = b.y;
            B_lds[c4*4+2][row] = b.z; B_lds[c4*4+3][row] = b.w;
        }
        __syncthreads();
        #pragma unroll
        for (int kk = 0; kk < 32; ++kk) {
            float4 a = *(const float4*)&A_lds[kk][ty * 4];
            float4 b = *(const float4*)&B_lds[kk][tx * 4];
            float av[4] = {a.x, a.y, a.z, a.w};
            float bv[4] = {b.x, b.y, b.z, b.w};
            #pragma unroll
            for (int i = 0; i < 4; ++i)
                #pragma unroll
                for (int j = 0; j < 4; ++j)
                    acc[i][j] = fmaf(av[i], bv[j], acc[i][j]);
        }
        __syncthreads();
    }
    float bj[4];
    #pragma unroll
    for (int j = 0; j < 4; ++j) bj[j] = bias ? bias[n0 + tx * 4 + j] : 0.f;
    #pragma unroll
    for (int i = 0; i < 4; ++i)
        #pragma unroll
        for (int j = 0; j < 4; ++j)
            C[(size_t)(t0 + ty * 4 + i) * cs + n0 + tx * 4 + j] = acc[i][j] + bj[j];
}

// ------------------------- encoder recurrence ------------------------------
// 256 blocks x 64 threads (1 wave). Block b owns h[4b..4b+4).
// LDS-resident W_hh (12 rows). 1 LL exchange per step (parity dbuf).
__global__ __launch_bounds__(64) void enc_seq(
    const float* __restrict__ Whh, const float* __restrict__ bhh,
    const float* __restrict__ gi,          // enc_gi [512][3072]
    float* __restrict__ enc_outs,          // [512][1024]
    u64* __restrict__ hb)                  // [2][1024] LL segs
{
    __shared__ float4 w4[12 * 256];
    __shared__ float h_lds[1024];
    __shared__ float gh_lds[12];
    __shared__ float bias_lds[12];
    const int lane = threadIdx.x, bid = blockIdx.x;
    const int j0 = bid * 4;
    for (int i = lane; i < 12 * 256; i += 64) {
        int r = i >> 8, c = i & 255;
        int grow = (r >> 2) * 1024 + j0 + (r & 3);
        w4[i] = *(const float4*)(Whh + (size_t)grow * 1024 + c * 4);
    }
    if (lane < 12) bias_lds[lane] = bhh[(lane >> 2) * 1024 + j0 + (lane & 3)];
    #pragma unroll
    for (int j = 0; j < 16; ++j) h_lds[lane + 64 * j] = 0.f;
    __syncthreads();

    for (int t = 0; t < T; ++t) {
        float gir = 0.f, giz = 0.f, gin = 0.f;
        if (lane < 4) {
            const float* gr = gi + (size_t)t * 3072 + j0 + lane;
            gir = gr[0]; giz = gr[1024]; gin = gr[2048];
        }
        for (int rr = 0; rr < 12; ++rr) {
            const float4* wrow = w4 + rr * 256;
            float acc = 0.f;
            #pragma unroll
            for (int i = 0; i < 4; ++i) {
                float4 wv = wrow[lane + 64 * i];
                float4 hv = ((const float4*)h_lds)[lane + 64 * i];
                acc += wv.x*hv.x + wv.y*hv.y + wv.z*hv.z + wv.w*hv.w;
            }
            #pragma unroll
            for (int o = 32; o; o >>= 1) acc += __shfl_xor(acc, o);
            if (lane == 0) gh_lds[rr] = acc + bias_lds[rr];
        }
        __syncthreads();
        if (lane < 4) {
            float r = sigmoidf_(gir + gh_lds[lane]);
            float z = sigmoidf_(giz + gh_lds[4 + lane]);
            float n = tanhf(gin + r * gh_lds[8 + lane]);
            float h2 = (1.f - z) * n + z * h_lds[j0 + lane];
            enc_outs[(size_t)t * 1024 + j0 + lane] = h2;   // for K3 / dec t=0
            ll_store(hb + (t & 1) * 1024 + j0 + lane, h2, (unsigned)(t + 1));
        }
        if (t < T - 1) {
            float hv[16];
            ll_poll16(hb + (t & 1) * 1024, (unsigned)(t + 1), lane, hv);
            #pragma unroll
            for (int j = 0; j < 16; ++j) h_lds[lane + 64 * j] = hv[j];
            __syncthreads();
        }
    }
}

// ------------------------- decoder recurrence ------------------------------
// 256 blocks x 64 threads (1 wave). Block b owns h[4b..4b+4), s[2b..2b+2).
// LDS-resident: dec_W_ih, dec_W_hh (12 rows each), attn_W h-half (2 rows),
// M (4 rows). 3 LL exchanges per step (SB, XB, HB; single-buffered — each
// buffer's next overwrite is 2 exchanges away, so no consumer can lag into it).
__global__ __launch_bounds__(64) void dec_seq(
    const float* __restrict__ Wih, const float* __restrict__ Whh,
    const float* __restrict__ bih, const float* __restrict__ bhh,
    const float* __restrict__ attnW,   // [512][2048]
    const float* __restrict__ attn_e,  // [512][512]
    const float* __restrict__ comb_e,  // [512][1024]
    const float* __restrict__ M,       // [1024][512]
    const float* __restrict__ enc_outs,
    float* __restrict__ H2,            // [512][1024] (for K5)
    u64* __restrict__ sb, u64* __restrict__ xb, u64* __restrict__ hb)
{
    __shared__ float4 wih4[12 * 256];
    __shared__ float4 whh4[12 * 256];
    __shared__ float4 aw4[2 * 256];
    __shared__ float4 m4[4 * 128];
    __shared__ float h_lds[1024];
    __shared__ float x_lds[1024];
    __shared__ float p_lds[512];
    __shared__ float gh_lds[12], gi_lds[12];
    __shared__ float bih_lds[12], bhh_lds[12];

    const int lane = threadIdx.x, bid = blockIdx.x;
    const int j0 = bid * 4, l0 = bid * 2;
    for (int i = lane; i < 12 * 256; i += 64) {
        int r = i >> 8, c = i & 255;
        int grow = (r >> 2) * 1024 + j0 + (r & 3);
        wih4[i] = *(const float4*)(Wih + (size_t)grow * 1024 + c * 4);
        whh4[i] = *(const float4*)(Whh + (size_t)grow * 1024 + c * 4);
    }
    for (int i = lane; i < 2 * 256; i += 64) {
        int r = i >> 8, c = i & 255;
        aw4[i] = *(const float4*)(attnW + (size_t)(l0 + r) * 2048 + 1024 + c * 4);
    }
    for (int i = lane; i < 4 * 128; i += 64) {
        int r = i >> 7, c = i & 127;
        m4[i] = *(const float4*)(M + (size_t)(j0 + r) * 512 + c * 4);
    }
    if (lane < 12) {
        int grow = (lane >> 2) * 1024 + j0 + (lane & 3);
        bih_lds[lane] = bih[grow]; bhh_lds[lane] = bhh[grow];
    }
    #pragma unroll
    for (int j = 0; j < 16; ++j)
        h_lds[lane + 64 * j] = enc_outs[(size_t)(T - 1) * 1024 + lane + 64 * j];
    __syncthreads();

    for (int t = 0; t < T; ++t) {
        const unsigned tag = (unsigned)(t + 1);
        // ---- prefetch per-step embedding terms ----
        float ae = 0.f, ce = 0.f;
        if ((lane & 31) == 0) ae = attn_e[(size_t)t * 512 + l0 + (lane >> 5)];
        if ((lane & 15) == 0) ce = comb_e[(size_t)t * 1024 + j0 + (lane >> 4)];

        // ---- s rows: 2 rows, 32 lanes each ----
        {
            const float4* arow = aw4 + (lane >> 5) * 256;
            const int q2 = lane & 31;
            float acc = 0.f;
            #pragma unroll
            for (int i = 0; i < 8; ++i) {
                float4 wv = arow[q2 + 32 * i];
                float4 hv = ((const float4*)h_lds)[q2 + 32 * i];
                acc += wv.x*hv.x + wv.y*hv.y + wv.z*hv.z + wv.w*hv.w;
            }
            #pragma unroll
            for (int o = 16; o; o >>= 1) acc += __shfl_xor(acc, o);
            if (q2 == 0) ll_store(sb + l0 + (lane >> 5), acc + ae, tag);
        }

        // ---- gh rows (overlap s propagation) ----
        for (int rr = 0; rr < 12; ++rr) {
            const float4* wrow = whh4 + rr * 256;
            float acc = 0.f;
            #pragma unroll
            for (int i = 0; i < 4; ++i) {
                float4 wv = wrow[lane + 64 * i];
                float4 hv = ((const float4*)h_lds)[lane + 64 * i];
                acc += wv.x*hv.x + wv.y*hv.y + wv.z*hv.z + wv.w*hv.w;
            }
            #pragma unroll
            for (int o = 32; o; o >>= 1) acc += __shfl_xor(acc, o);
            if (lane == 0) gh_lds[rr] = acc + bhh_lds[rr];
        }

        // ---- poll s, softmax (8 values/lane) ----
        float sv[8];
        ll_poll8(sb, tag, lane, sv);
        float mx = sv[0];
        #pragma unroll
        for (int j = 1; j < 8; ++j) mx = fmaxf(mx, sv[j]);
        #pragma unroll
        for (int o = 32; o; o >>= 1) mx = fmaxf(mx, __shfl_xor(mx, o));
        float pv[8], lsum = 0.f;
        #pragma unroll
        for (int j = 0; j < 8; ++j) { pv[j] = expf(sv[j] - mx); lsum += pv[j]; }
        #pragma unroll
        for (int o = 32; o; o >>= 1) lsum += __shfl_xor(lsum, o);
        #pragma unroll
        for (int j = 0; j < 8; ++j) p_lds[lane + 64 * j] = pv[j];
        __syncthreads();

        // ---- x = relu(ce + (M@p)/lsum): 4 rows, 16 lanes each ----
        {
            const int d = lane >> 4, q = lane & 15;
            const float4* mr = m4 + d * 128;
            float acc = 0.f;
            #pragma unroll
            for (int i = 0; i < 8; ++i) {
                float4 mv = mr[q + 16 * i];
                float4 pp = ((const float4*)p_lds)[q + 16 * i];
                acc += mv.x*pp.x + mv.y*pp.y + mv.z*pp.z + mv.w*pp.w;
            }
            #pragma unroll
            for (int o = 8; o; o >>= 1) acc += __shfl_xor(acc, o);
            if (q == 0)
                ll_store(xb + j0 + d, fmaxf(ce + acc / lsum, 0.f), tag);
        }

        // ---- poll x, gi rows ----
        float xv[16];
        ll_poll16(xb, tag, lane, xv);
        #pragma unroll
        for (int j = 0; j < 16; ++j) x_lds[lane + 64 * j] = xv[j];
        __syncthreads();
        for (int rr = 0; rr < 12; ++rr) {
            const float4* wrow = wih4 + rr * 256;
            float acc = 0.f;
            #pragma unroll
            for (int i = 0; i < 4; ++i) {
                float4 wv = wrow[lane + 64 * i];
                float4 xvv = ((const float4*)x_lds)[lane + 64 * i];
                acc += wv.x*xvv.x + wv.y*xvv.y + wv.z*xvv.z + wv.w*xvv.w;
            }
            #pragma unroll
            for (int o = 32; o; o >>= 1) acc += __shfl_xor(acc, o);
            if (lane == 0) gi_lds[rr] = acc + bih_lds[rr];
        }
        __syncthreads();

        // ---- gates ----
        if (lane < 4) {
            float r = sigmoidf_(gi_lds[lane] + gh_lds[lane]);
            float z = sigmoidf_(gi_lds[4 + lane] + gh_lds[4 + lane]);
            float n = tanhf(gi_lds[8 + lane] + r * gh_lds[8 + lane]);
            float h2 = (1.f - z) * n + z * h_lds[j0 + lane];
            H2[(size_t)t * 1024 + j0 + lane] = h2;          // for K5
            ll_store(hb + j0 + lane, h2, tag);
        }
        if (t < T - 1) {
            float hv[16];
            ll_poll16(hb, tag, lane, hv);
            #pragma unroll
            for (int j = 0; j < 16; ++j) h_lds[lane + 64 * j] = hv[j];
            __syncthreads();
        }
    }
}

// ------------------- output GEMM + fused LSE partials ----------------------
// grid (250, 4), block 256; tile 128(cols) x 128(rows), thread 8x8.
__global__ __launch_bounds__(256) void out_gemm_lse(
    const float* __restrict__ H2, const float* __restrict__ outW,
    const float* __restrict__ outB, const int* __restrict__ tgt,
    float* __restrict__ lsep, float* __restrict__ tgtlog)
{
    __shared__ float A_lds[32][128];
    __shared__ float B_lds[32][128];
    const int tid = threadIdx.x;
    const int tx = tid & 15, ty = tid >> 4;
    const int c0 = blockIdx.x * 128, r0 = blockIdx.y * 128;
    float acc[8][8] = {};

    for (int k0 = 0; k0 < 1024; k0 += 32) {
        #pragma unroll
        for (int q = 0; q < 4; ++q) {
            int f4 = tid + q * 256;          // 0..1023
            int row = f4 >> 3, c4 = f4 & 7;
            float4 a = *(const float4*)(H2 + (size_t)(r0 + row) * 1024 + k0 + c4 * 4);
            A_lds[c4*4+0][row] = a.x; A_lds[c4*4+1][row] = a.y;
            A_lds[c4*4+2][row] = a.z; A_lds[c4*4+3][row] = a.w;
            float4 b = *(const float4*)(outW + (size_t)(c0 + row) * 1024 + k0 + c4 * 4);
            B_lds[c4*4+0][row] = b.x; B_lds[c4*4+1][row] = b.y;
            B_lds[c4*4+2][row] = b.z; B_lds[c4*4+3][row] = b.w;
        }
        __syncthreads();
        #pragma unroll
        for (int kk = 0; kk < 32; ++kk) {
            float4 a0 = *(const float4*)&A_lds[kk][ty * 8];
            float4 a1 = *(const float4*)&A_lds[kk][ty * 8 + 4];
            float4 b0 = *(const float4*)&B_lds[kk][tx * 8];
            float4 b1 = *(const float4*)&B_lds[kk][tx * 8 + 4];
            float av[8] = {a0.x,a0.y,a0.z,a0.w,a1.x,a1.y,a1.z,a1.w};
            float bv[8] = {b0.x,b0.y,b0.z,b0.w,b1.x,b1.y,b1.z,b1.w};
            #pragma unroll
            for (int i = 0; i < 8; ++i)
                #pragma unroll
                for (int j = 0; j < 8; ++j)
                    acc[i][j] = fmaf(av[i], bv[j], acc[i][j]);
        }
        __syncthreads();
    }
    float bj[8];
    #pragma unroll
    for (int j = 0; j < 8; ++j) bj[j] = outB[c0 + tx * 8 + j];

    const int bx = blockIdx.x;
    #pragma unroll
    for (int i = 0; i < 8; ++i) {
        int t = r0 + ty * 8 + i;
        float rowv[8];
        float vmax = -INFINITY;
        #pragma unroll
        for (int j = 0; j < 8; ++j) {
            rowv[j] = acc[i][j] + bj[j];
            vmax = fmaxf(vmax, rowv[j]);
        }
        float ssum = 0.f;
        #pragma unroll
        for (int j = 0; j < 8; ++j) ssum += expf(rowv[j] - vmax);
        #pragma unroll
        for (int o = 1; o < 16; o <<= 1) {
            float om = __shfl_xor(vmax, o);
            float os = __shfl_xor(ssum, o);
            float nm = fmaxf(vmax, om);
            ssum = ssum * expf(vmax - nm) + os * expf(om - nm);
            vmax = nm;
        }
        if (tx == 0)
            *(float2*)&lsep[((size_t)t * 250 + bx) * 2] = make_float2(vmax, ssum);
        int tv = tgt[t];
        if (tv >= c0 && tv < c0 + 128) {
            int rel = tv - c0;
            if ((rel >> 3) == tx) tgtlog[t] = rowv[rel & 7];
        }
    }
}

// ------------------------- final combine -----------------------------------
__global__ __launch_bounds__(512) void lse_combine(
    const float* __restrict__ lsep, const float* __restrict__ tgtlog,
    float* __restrict__ out)
{
    const int t = threadIdx.x;     // 0..511
    float m = -INFINITY, s = 0.f;
    for (int cb = 0; cb < 250; ++cb) {
        float2 p = *(const float2*)&lsep[((size_t)t * 250 + cb) * 2];
        float nm = fmaxf(m, p.x);
        s = s * expf(m - nm) + p.y * expf(p.x - nm);
        m = nm;
    }
    float nll = (m + logf(s)) - tgtlog[t];
    __shared__ float red[8];
    float v = nll;
    #pragma unroll
    for (int o = 32; o; o >>= 1) v += __shfl_xor(v, o);
    if ((t & 63) == 0) red[t >> 6] = v;
    __syncthreads();
    if (t == 0) {
        float sum = 0.f;
        for (int w = 0; w < 8; ++w) sum += red[w];
        out[0] = sum / 512.f;
    }
}

// ---------------------------------------------------------------------------
extern "C" void kernel_launch(void* const* d_in, const int* in_sizes, int n_in,
                              void* d_out, int out_size, void* d_ws, size_t ws_size,
                              hipStream_t stream) {
    const int*   input   = (const int*)d_in[0];
    const int*   target  = (const int*)d_in[1];
    const float* enc_emb = (const float*)d_in[2];
    const float* eWih    = (const float*)d_in[3];
    const float* eWhh    = (const float*)d_in[4];
    const float* ebih    = (const float*)d_in[5];
    const float* ebhh    = (const float*)d_in[6];
    const float* dec_emb = (const float*)d_in[7];
    const float* attnW   = (const float*)d_in[8];
    const float* attnB   = (const float*)d_in[9];
    const float* combW   = (const float*)d_in[10];
    const float* combB   = (const float*)d_in[11];
    const float* dWih    = (const float*)d_in[12];
    const float* dWhh    = (const float*)d_in[13];
    const float* dbih    = (const float*)d_in[14];
    const float* dbhh    = (const float*)d_in[15];
    const float* outW    = (const float*)d_in[16];
    const float* outB    = (const float*)d_in[17];
    float* out = (float*)d_out;

    float* wsf = (float*)d_ws;
    u64* encHB = (u64*)d_ws;                              // bytes [0,16384): [2][1024]
    u64* SB    = (u64*)((char*)d_ws + 16384);             // [16384,20480): [512]
    u64* XB    = (u64*)((char*)d_ws + 20480);             // [20480,28672): [1024]
    u64* HB    = (u64*)((char*)d_ws + 28672);             // [28672,36864): [1024]
    float* enc_gi   = wsf + 9216;      // [512][3072]
    float* enc_outs = wsf + 1582080;   // [512][1024]
    float* attn_e   = wsf + 2106368;   // [512][512]
    float* comb_e   = wsf + 2368512;   // [512][1024]
    float* Mws      = wsf + 2892800;   // [1024][512]
    float* H2       = wsf + 3417088;   // [512][1024]
    float* lsep     = wsf + 3941376;   // [512][250][2]
    float* tgtlog   = wsf + 4197376;   // [512]

    hipMemsetAsync(d_ws, 0, 36864, stream);   // LL mailboxes (tags start < 1)

    // K1: token-indexed precomputes
    gemm_tn<<<dim3(48, 8), 256, 0, stream>>>(enc_emb, 1024, 0, input, 1,
        eWih, 1024, 0, ebih, enc_gi, 3072, 1024);
    gemm_tn<<<dim3(8, 8), 256, 0, stream>>>(dec_emb, 1024, 0, target, 2,
        attnW, 2048, 0, attnB, attn_e, 512, 1024);
    gemm_tn<<<dim3(16, 8), 256, 0, stream>>>(dec_emb, 1024, 0, target, 2,
        combW, 2048, 0, combB, comb_e, 1024, 1024);

    // K2: encoder recurrence
    enc_seq<<<256, 64, 0, stream>>>(eWhh, ebhh, enc_gi, enc_outs, encHB);

    // K3: M = comb_W[:, H:] @ enc_outs^T
    gemm_tn<<<dim3(8, 16), 256, 0, stream>>>(combW, 2048, 1024, nullptr, 0,
        enc_outs, 1024, 0, nullptr, Mws, 512, 1024);

    // K4: decoder recurrence
    dec_seq<<<256, 64, 0, stream>>>(dWih, dWhh, dbih, dbhh, attnW,
        attn_e, comb_e, Mws, enc_outs, H2, SB, XB, HB);

    // K5: logits GEMM + fused LSE partials
    out_gemm_lse<<<dim3(250, 4), 256, 0, stream>>>(H2, outW, outB, target,
        lsep, tgtlog);

    // K6: combine -> scalar
    lse_combine<<<1, 512, 0, stream>>>(lsep, tgtlog, out);
}